// Round 3
// baseline (342.224 us; speedup 1.0000x reference)
//
#include <hip/hip_runtime.h>
#include <cfloat>

// Problem constants (reference: B=32, C=256, H=W=64, nh=4, hid=64, S=40)
#define B_    32
#define C_    256
#define HW_   4096
#define SSEL_ 40
#define GADD_ 0.0075f   // 0.3 * (1/40): pixel_imp collapses to 1/S exactly

typedef __attribute__((ext_vector_type(8))) short  short8;   // 8 bf16 (4 VGPR)
typedef __attribute__((ext_vector_type(4))) float  floatx4;  // MFMA C/D

__device__ __forceinline__ unsigned short f2bf(float f) {    // RNE f32->bf16
    unsigned u = __float_as_uint(f);
    return (unsigned short)((u + 0x7FFFu + ((u >> 16) & 1u)) >> 16);
}
__device__ __forceinline__ float sigm(float v) { return 1.f / (1.f + __expf(-v)); }

// ---------------------------------------------------------------------------
// K0: w1 fp32 -> bf16 (64x256, 32 KB; L2/L3-resident for all K1 blocks)
// ---------------------------------------------------------------------------
__global__ __launch_bounds__(256) void k_cvt_w1(
    const float* __restrict__ w1, unsigned short* __restrict__ w1b)
{
    const int i = blockIdx.x * 256 + threadIdx.x;   // grid 64 -> 16384
    w1b[i] = f2bf(w1[i]);
}

// ---------------------------------------------------------------------------
// K1: fused MLP (MFMA) + importance + out-write. 64-px tile, 2048 blocks.
//   H1[64][64px] = relu(W1@X + b1) via mfma_f32_16x16x32_bf16
//   m = 0.175*sum_h sigmoid(W2@H1 + b2);  out = x * m  (x re-read, L2-warm)
// v2 post-mortem: fp32 VALU GEMM floor ~16K cyc/block (52% VALUBusy, 100us).
// MFMA issue for the same tile: 32 mfma/wave ~150 cyc -> HBM-streaming-bound.
// Layouts (guide, m89/m91-verified): A[m=lane&15][k=quad*8+j] (k-contig ->
// W1 row-major bf16 direct from global); B[k=quad*8+j][n=lane&15] (k-contig
// -> XT[px][ch] in LDS, transposed at staging, row stride 264 bf16 so b128
// reads are 2-way/free); D col=lane&15 (px), row=quad*4+r (hid-local).
// ---------------------------------------------------------------------------
__global__ __launch_bounds__(256, 4) void k_mlp_mfma(
    const float* __restrict__ x, const unsigned short* __restrict__ w1b,
    const float* __restrict__ b1, const float* __restrict__ w2,
    const float* __restrict__ b2, float* __restrict__ imp,
    float* __restrict__ out)
{
    __shared__ __align__(16) unsigned short XT[64 * 264];  // 33792 B
    __shared__ float4 SAB[256];                            // importance partials
    __shared__ float  m_s[64];

    const int t  = threadIdx.x;
    const int b  = blockIdx.x >> 6;            // 64 tiles per batch
    const int p0 = (blockIdx.x & 63) * 64;
    const size_t xb = ((size_t)b << 20) + p0;  // b*C*HW + p0

    // ---- stage x tile -> bf16 transposed LDS; fold sum|x| (fp32) ----
    const int pxq = t >> 4;     // px quad: px 4*pxq .. +3
    const int chg = t & 15;     // ch group
    float4 sa = make_float4(0.f, 0.f, 0.f, 0.f);
    #pragma unroll
    for (int i = 0; i < 4; ++i) {
        const int cb = chg * 4 + i * 64;       // 4 consecutive ch rows
        float v[4][4];
        #pragma unroll
        for (int r = 0; r < 4; ++r) {
            const float4 t4 = *(const float4*)(x + xb + (size_t)(cb + r) * HW_ + pxq * 4);
            v[r][0] = t4.x; v[r][1] = t4.y; v[r][2] = t4.z; v[r][3] = t4.w;
        }
        #pragma unroll
        for (int r = 0; r < 4; ++r) {
            sa.x += fabsf(v[r][0]); sa.y += fabsf(v[r][1]);
            sa.z += fabsf(v[r][2]); sa.w += fabsf(v[r][3]);
        }
        #pragma unroll
        for (int p = 0; p < 4; ++p) {          // transpose: 4 bf16 ch per px
            ushort4 w;
            w.x = f2bf(v[0][p]); w.y = f2bf(v[1][p]);
            w.z = f2bf(v[2][p]); w.w = f2bf(v[3][p]);
            *(ushort4*)(XT + (pxq * 4 + p) * 264 + cb) = w;
        }
    }
    SAB[chg * 16 + pxq] = sa;
    __syncthreads();

    // importance: per px, sum partials over the 16 ch-groups
    if (t < 16) {
        float4 s = make_float4(0.f, 0.f, 0.f, 0.f);
        #pragma unroll
        for (int g = 0; g < 16; ++g) {
            const float4 v = SAB[g * 16 + t];
            s.x += v.x; s.y += v.y; s.z += v.z; s.w += v.w;
        }
        *(float4*)(imp + ((size_t)b << 12) + p0 + t * 4) = s;
    }

    // ---- MFMA: wave w owns px 16w..+15 (all 64 hid in-register) ----
    const int lane = t & 63, wave = t >> 6;
    const int col = lane & 15, quad = lane >> 4;

    short8 bfrag[8];
    const unsigned short* xr = XT + (wave * 16 + col) * 264;
    #pragma unroll
    for (int ks = 0; ks < 8; ++ks)
        bfrag[ks] = *(const short8*)(xr + ks * 32 + quad * 8);

    floatx4 acc[4];
    #pragma unroll
    for (int ht = 0; ht < 4; ++ht) acc[ht] = (floatx4){0.f, 0.f, 0.f, 0.f};

    #pragma unroll
    for (int ks = 0; ks < 8; ++ks) {
        #pragma unroll
        for (int ht = 0; ht < 4; ++ht) {
            const short8 af = *(const short8*)(w1b + (ht * 16 + col) * 256 + ks * 32 + quad * 8);
            acc[ht] = __builtin_amdgcn_mfma_f32_16x16x32_bf16(af, bfrag[ks], acc[ht], 0, 0, 0);
        }
    }

    // ---- layer 2 in-register: lane holds 16 hid (4 ht x 4 r) for px=16w+col
    float s0 = 0.f, s1 = 0.f, s2 = 0.f, s3 = 0.f;
    #pragma unroll
    for (int ht = 0; ht < 4; ++ht)
        #pragma unroll
        for (int r = 0; r < 4; ++r) {
            const int hid = ht * 16 + quad * 4 + r;
            const float h1 = fmaxf(acc[ht][r] + b1[hid], 0.f);
            s0 = fmaf(w2[hid],       h1, s0);
            s1 = fmaf(w2[64 + hid],  h1, s1);
            s2 = fmaf(w2[128 + hid], h1, s2);
            s3 = fmaf(w2[192 + hid], h1, s3);
        }
    // reduce the 4 lane-quads (hid partition)
    s0 += __shfl_xor(s0, 16, 64); s0 += __shfl_xor(s0, 32, 64);
    s1 += __shfl_xor(s1, 16, 64); s1 += __shfl_xor(s1, 32, 64);
    s2 += __shfl_xor(s2, 16, 64); s2 += __shfl_xor(s2, 32, 64);
    s3 += __shfl_xor(s3, 16, 64); s3 += __shfl_xor(s3, 32, 64);
    if (quad == 0) {
        const float ssum = sigm(s0 + b2[0]) + sigm(s1 + b2[1])
                         + sigm(s2 + b2[2]) + sigm(s3 + b2[3]);
        m_s[wave * 16 + col] = 0.175f * ssum;
    }
    __syncthreads();

    // ---- fused out-write: out = x * m (fp32 re-read; tile is L2-warm) ----
    const int pxl = (t & 15) * 4;
    const float4 mv = *(const float4*)(m_s + pxl);
    #pragma unroll
    for (int i = 0; i < 16; ++i) {
        const int c = (t >> 4) + i * 16;
        const size_t a = xb + (size_t)c * HW_ + pxl;
        const float4 xv = *(const float4*)(x + a);
        float4 o;
        o.x = xv.x * mv.x; o.y = xv.y * mv.y;
        o.z = xv.z * mv.z; o.w = xv.w * mv.w;
        *(float4*)(out + a) = o;
    }
}

// ---------------------------------------------------------------------------
// K2: per-batch top-40 (wave 0, verified register alg) -> selected px in LDS,
// then all 256 threads fix up: out[b,c,p] += x[b,c,p]*GADD for 40 px.
// Replaces the full-x re-read of the old K3 (134 MB) with ~60 MB scattered.
// ---------------------------------------------------------------------------
__global__ __launch_bounds__(256) void k_topk_fix(
    const float* __restrict__ imp, const float* __restrict__ x,
    float* __restrict__ out)
{
    __shared__ int sel[SSEL_];
    const int b = blockIdx.x, t = threadIdx.x;

    if (t < 64) {
        const int lane = t;
        const float* __restrict__ ib = imp + (size_t)b * HW_;
        float v[64];
        #pragma unroll
        for (int i = 0; i < 64; ++i) v[i] = ib[i * 64 + lane];
        float g[8];
        #pragma unroll
        for (int k = 0; k < 8; ++k) {
            float gm = v[8 * k];
            #pragma unroll
            for (int i = 1; i < 8; ++i) gm = fmaxf(gm, v[8 * k + i]);
            g[k] = gm;
        }
        for (int it = 0; it < SSEL_; ++it) {
            float lm = g[0];
            #pragma unroll
            for (int k = 1; k < 8; ++k) lm = fmaxf(lm, g[k]);
            float wm = lm;
            #pragma unroll
            for (int off = 32; off >= 1; off >>= 1)
                wm = fmaxf(wm, __shfl_xor(wm, off, 64));
            #pragma unroll
            for (int k = 0; k < 8; ++k) {
                if (__any(g[k] == wm)) {
                    int gi = -1;
                    #pragma unroll
                    for (int i = 0; i < 8; ++i) {
                        if (v[8 * k + i] == wm) {
                            gi = (8 * k + i) * 64 + lane;
                            v[8 * k + i] = -FLT_MAX;
                        }
                    }
                    float gm = v[8 * k];
                    #pragma unroll
                    for (int i = 1; i < 8; ++i) gm = fmaxf(gm, v[8 * k + i]);
                    g[k] = gm;
                    if (gi >= 0) sel[it] = gi;   // unique owner lane
                }
            }
        }
    }
    __syncthreads();

    const size_t base = ((size_t)b << 20) + (size_t)t * HW_;  // c = t
    #pragma unroll 4
    for (int s = 0; s < SSEL_; ++s) {
        const int p = sel[s];
        out[base + p] += x[base + p] * GADD_;
    }
}

extern "C" void kernel_launch(void* const* d_in, const int* in_sizes, int n_in,
                              void* d_out, int out_size, void* d_ws, size_t ws_size,
                              hipStream_t stream)
{
    const float* x  = (const float*)d_in[0];
    const float* w1 = (const float*)d_in[1];  // gm_w1 [64,256]
    const float* b1 = (const float*)d_in[2];  // gm_b1 [64]
    const float* w2 = (const float*)d_in[3];  // gm_w2 [4,64]
    const float* b2 = (const float*)d_in[4];  // gm_b2 [4]
    // d_in[5..9] (qkv_w, ge_*) provably do not affect the output: softmax rows
    // mean to 1/S regardless of scores, so pixel_imp == 1/40 exactly.

    float*          imp = (float*)d_ws;                              // 512 KB
    unsigned short* w1b = (unsigned short*)((char*)d_ws + 512 * 1024); // 32 KB
    float*          out = (float*)d_out;

    k_cvt_w1<<<dim3(64), dim3(256), 0, stream>>>(w1, w1b);
    k_mlp_mfma<<<dim3(B_ * (HW_ / 64)), dim3(256), 0, stream>>>(x, w1b, b1, w2, b2, imp, out);
    k_topk_fix<<<dim3(B_), dim3(256), 0, stream>>>(imp, x, out);
}